// Round 19
// baseline (144.944 us; speedup 1.0000x reference)
//
#include <hip/hip_runtime.h>

#define N_NODES 50000
#define N_EDGES 800000
#define N_TOT   850000   // edges + self loops
#define FIN 27
#define NCAND 8192
#define CTXD 32
#define NBUCK 7
#define NEG 0.2f
#define MAXDEG 64        // padded CSR row; P(deg>64) ~ 1e-19 per node at lambda=17
#define NSLICE 8         // dst slices = XCD count; slice = dst & 7
#define SL_N 6250        // nodes per slice (50000/8)
#define EPB 1024         // edges scanned per fill block
#define NCHUNK 831       // ceil(850000/1024)
#define FILLB (NCHUNK * NSLICE)   // 6648 fill blocks

typedef unsigned short ushortT;

__device__ __forceinline__ float bfu(ushortT u) { return __uint_as_float(((unsigned)u) << 16); }
__device__ __forceinline__ unsigned f2b(float f) {
    unsigned bits = __float_as_uint(f);
    return (bits + 0x7FFFu + ((bits >> 16) & 1u)) >> 16;
}
// slot for node d: slice-exclusive contiguous block (degS and csr16 rows)
__device__ __forceinline__ int degslot(int d) { return (d & 7) * SL_N + (d >> 3); }

// ============ Kernel A: XCD-sliced scatter CSR fill || prep1 || misc precompute ============
// Scatter-fill cost model (R17): not edge reads (~12us of L3 hits), but the RFO
// line-fill each random 2B store triggers (850K ~900cy allocates + 34MB writeback).
// This round: __builtin_nontemporal_store on the scatter store to request
// no-allocate/streaming write policy.
__global__ __launch_bounds__(256) void kernelA(
    const int* __restrict__ e_src, const int* __restrict__ e_dst,
    int* __restrict__ degS, ushortT* __restrict__ csr16,
    const float* __restrict__ x, const float* __restrict__ W1,
    const float* __restrict__ as1, const float* __restrict__ ad1,
    const float* __restrict__ W2, const float* __restrict__ as2, const float* __restrict__ ad2,
    const float* __restrict__ donor, const float* __restrict__ sW1, const float* __restrict__ sb1,
    const float* __restrict__ lW1, const float* __restrict__ lb1,
    unsigned* __restrict__ xbu, float* __restrict__ asb, float* __restrict__ adb,
    float* __restrict__ u2s, float* __restrict__ u2d,
    float* __restrict__ cs, float* __restrict__ cl, float* __restrict__ pooledP) {
    __shared__ float u1[256];
    int bid = blockIdx.x;
    int t = threadIdx.x;

    if (bid < FILLB) {
        // ---- sliced scatter fill (slice pinned to XCD by round-robin dispatch) ----
        int chunk = bid >> 3;
        int slice = bid & 7;
        int e0 = chunk * EPB;
#pragma unroll
        for (int i = 0; i < EPB / 256; i++) {
            int e = e0 + i * 256 + t;
            if (e < N_TOT) {
                int d = (e < N_EDGES) ? e_dst[e] : (e - N_EDGES);
                if ((d & 7) == slice) {
                    int s = (e < N_EDGES) ? e_src[e] : d;
                    int slot = degslot(d);
                    int p = atomicAdd(&degS[slot], 1);
                    if (p < MAXDEG)
                        __builtin_nontemporal_store((ushortT)s, csr16 + ((long)slot << 6) + p);
                }
            }
        }
    } else if (bid < FILLB + 196) {
        // ---- prep1: compute u1 locally, then per-node dots + bf16 pack ----
        if (t < 4 * FIN) {
            int h = t / FIN, k = t % FIN;
            float s = 0.f;
            for (int f = 0; f < 64; f++) s += W1[k * 256 + h * 64 + f] * as1[h * 64 + f];
            u1[h * 32 + k] = s;
        } else if (t >= 128 && t < 128 + 4 * FIN) {
            int tt = t - 128;
            int h = tt / FIN, k = tt % FIN;
            float d = 0.f;
            for (int f = 0; f < 64; f++) d += W1[k * 256 + h * 64 + f] * ad1[h * 64 + f];
            u1[128 + h * 32 + k] = d;
        }
        __syncthreads();
        int n = (bid - FILLB) * 256 + t;
        if (n < N_NODES) {
            float xr[FIN];
#pragma unroll
            for (int k = 0; k < FIN; k++) xr[k] = x[(long)n * FIN + k];
            float s0 = 0, s1 = 0, s2 = 0, s3 = 0, d0 = 0, d1 = 0, d2 = 0, d3 = 0;
#pragma unroll
            for (int k = 0; k < FIN; k++) {
                float xv = xr[k];
                s0 = fmaf(xv, u1[0 * 32 + k], s0);
                s1 = fmaf(xv, u1[1 * 32 + k], s1);
                s2 = fmaf(xv, u1[2 * 32 + k], s2);
                s3 = fmaf(xv, u1[3 * 32 + k], s3);
                d0 = fmaf(xv, u1[128 + 0 * 32 + k], d0);
                d1 = fmaf(xv, u1[128 + 1 * 32 + k], d1);
                d2 = fmaf(xv, u1[128 + 2 * 32 + k], d2);
                d3 = fmaf(xv, u1[128 + 3 * 32 + k], d3);
            }
            float4 sv; sv.x = s0; sv.y = s1; sv.z = s2; sv.w = s3;
            float4 dv; dv.x = d0; dv.y = d1; dv.z = d2; dv.w = d3;
            *(float4*)(asb + n * 4) = sv;
            *(float4*)(adb + n * 4) = dv;
#pragma unroll
            for (int i = 0; i < 16; i++) {
                float a = (2 * i < FIN) ? xr[2 * i] : 0.f;
                float b = (2 * i + 1 < FIN) ? xr[2 * i + 1] : 0.f;
                xbu[(long)n * 16 + i] = f2b(a) | (f2b(b) << 16);
            }
        }
    } else {
        // ---- misc precompute ----
        pooledP[t] = 0.f;
        pooledP[256 + t] = 0.f;
        {
            int h = t >> 6, k = t & 63;
            float s = 0.f, d = 0.f;
            for (int f = 0; f < 64; f++) {
                float w = W2[k * 256 + h * 64 + f];
                s += w * as2[h * 64 + f];
                d += w * ad2[h * 64 + f];
            }
            u2s[h * 64 + k] = s;
            u2d[h * 64 + k] = d;
        }
        if (t < 64) {
            float a = sb1[t];
            float b = lb1[t];
            for (int m = 0; m < CTXD; m++) {
                float d = donor[m];
                a += d * sW1[(64 + m) * 64 + t];
                b += d * lW1[(64 + m) * 64 + t];
            }
            cs[t] = a;
            cl[t] = b;
        }
    }
}

// ---------------- fused attention + aggregation (wave per dst, single padded tile) ----------------
template <int FEATS, bool USECAND>
__global__ __launch_bounds__(256) void msg_kernel(
    const ushortT* __restrict__ feat, const float* __restrict__ asb,
    const float* __restrict__ adb, const int* __restrict__ degS,
    const ushortT* __restrict__ csr16, const int* __restrict__ cand,
    float* __restrict__ agg, int ndst) {
    __shared__ float wls[4][256];
    __shared__ int   sls[4][64];
    int wslot = threadIdx.x >> 6;
    int lane = threadIdx.x & 63;
    int wid = (blockIdx.x * 256 + threadIdx.x) >> 6;
    if (wid >= ndst) return;
    int dst = USECAND ? cand[wid] : wid;
    const float4 ad4 = *(const float4*)(adb + dst * 4);
    int slot = degslot(dst);
    int cnt = min(degS[slot], MAXDEG);
    float a0 = 0, a1 = 0, a2 = 0, a3 = 0;
    float d0 = 0, d1 = 0, d2 = 0, d3 = 0;
    const int f = lane & (FEATS - 1);
    {
        float w0 = 0, w1 = 0, w2 = 0, w3 = 0;
        int sj = dst;
        if (lane < cnt) {
            sj = (int)csr16[((long)slot << 6) + lane];
            const float4 as4 = *(const float4*)(asb + sj * 4);
            float e0 = as4.x + ad4.x; e0 = fmaxf(e0, NEG * e0); w0 = __expf(e0);
            float e1 = as4.y + ad4.y; e1 = fmaxf(e1, NEG * e1); w1 = __expf(e1);
            float e2 = as4.z + ad4.z; e2 = fmaxf(e2, NEG * e2); w2 = __expf(e2);
            float e3 = as4.w + ad4.w; e3 = fmaxf(e3, NEG * e3); w3 = __expf(e3);
            d0 = w0; d1 = w1; d2 = w2; d3 = w3;
        }
        float4 wv; wv.x = w0; wv.y = w1; wv.z = w2; wv.w = w3;
        *(float4*)&wls[wslot][lane * 4] = wv;
        sls[wslot][lane] = sj;
        asm volatile("" ::: "memory");   // keep DS write before DS reads (in-order per wave)
        if (FEATS == 32) {
            int iters = (cnt + 1) >> 1;
            int half = lane >> 5;
#pragma unroll 4
            for (int it = 0; it < iters; ++it) {
                int e = it * 2 + half;              // pad slot has w=0, src=dst
                int s = sls[wslot][e];
                float4 w4 = *(const float4*)&wls[wslot][e * 4];
                float fv = bfu(feat[(long)s * FEATS + f]);
                a0 = fmaf(w4.x, fv, a0);
                a1 = fmaf(w4.y, fv, a1);
                a2 = fmaf(w4.z, fv, a2);
                a3 = fmaf(w4.w, fv, a3);
            }
        } else {
#pragma unroll 4
            for (int e = 0; e < cnt; ++e) {
                int s = sls[wslot][e];
                float4 w4 = *(const float4*)&wls[wslot][e * 4];
                float fv = bfu(feat[(long)s * FEATS + f]);
                a0 = fmaf(w4.x, fv, a0);
                a1 = fmaf(w4.y, fv, a1);
                a2 = fmaf(w4.z, fv, a2);
                a3 = fmaf(w4.w, fv, a3);
            }
        }
    }
#pragma unroll
    for (int o = 32; o > 0; o >>= 1) {
        d0 += __shfl_xor(d0, o, 64);
        d1 += __shfl_xor(d1, o, 64);
        d2 += __shfl_xor(d2, o, 64);
        d3 += __shfl_xor(d3, o, 64);
    }
    if (FEATS == 32) {
        a0 += __shfl_xor(a0, 32, 64);
        a1 += __shfl_xor(a1, 32, 64);
        a2 += __shfl_xor(a2, 32, 64);
        a3 += __shfl_xor(a3, 32, 64);
    }
    if (lane < FEATS) {
        float4 r;
        r.x = a0 * (0.25f / d0);
        r.y = a1 * (0.25f / d1);
        r.z = a2 * (0.25f / d2);
        r.w = a3 * (0.25f / d3);
        *(float4*)(agg + (long)wid * (FEATS * 4) + lane * 4) = r;
    }
}

// ---------------- post-aggregation GEMM, layer 1 + fused layer-2 attention dots ----------------
__global__ __launch_bounds__(256) void gemm1_kernel(
    const float* __restrict__ agg1, const float* __restrict__ W1,
    const float* __restrict__ b1, const float* __restrict__ u2s,
    const float* __restrict__ u2d, ushortT* __restrict__ hmid_b,
    float* __restrict__ asb, float* __restrict__ adb) {
    __shared__ float sagg[16 * 128];   // 8 KB
    __shared__ float vsh[16][65];      // padded (conflict-free column reads)
    int t = threadIdx.x;
    int n0 = blockIdx.x * 16;          // N_NODES = 16 * 3125
    {
        const float4* src = (const float4*)(agg1 + (long)n0 * 128);
        float4* dst = (float4*)sagg;
        dst[t] = src[t];
        dst[t + 256] = src[t + 256];
    }
    __syncthreads();
    int r0 = (t >> 6) * 4;             // wave's first node (local)
    int f = t & 63;
    float bb = b1[f];
    float accA = bb, accB = bb, accC = bb, accD = bb;
    const float* pA = sagg + (r0 + 0) * 128;
    const float* pB = sagg + (r0 + 1) * 128;
    const float* pC = sagg + (r0 + 2) * 128;
    const float* pD = sagg + (r0 + 3) * 128;
#pragma unroll
    for (int k = 0; k < FIN; k++) {
        const float* wr = W1 + k * 256 + f;
        float w0 = wr[0], w1 = wr[64], w2 = wr[128], w3 = wr[192];
        float4 aA = *(const float4*)(pA + k * 4);
        float4 aB = *(const float4*)(pB + k * 4);
        float4 aC = *(const float4*)(pC + k * 4);
        float4 aD = *(const float4*)(pD + k * 4);
        accA = fmaf(aA.x, w0, accA); accA = fmaf(aA.y, w1, accA);
        accA = fmaf(aA.z, w2, accA); accA = fmaf(aA.w, w3, accA);
        accB = fmaf(aB.x, w0, accB); accB = fmaf(aB.y, w1, accB);
        accB = fmaf(aB.z, w2, accB); accB = fmaf(aB.w, w3, accB);
        accC = fmaf(aC.x, w0, accC); accC = fmaf(aC.y, w1, accC);
        accC = fmaf(aC.z, w2, accC); accC = fmaf(aC.w, w3, accC);
        accD = fmaf(aD.x, w0, accD); accD = fmaf(aD.y, w1, accD);
        accD = fmaf(aD.z, w2, accD); accD = fmaf(aD.w, w3, accD);
    }
    int n = n0 + r0;
    float v;
    v = accA; v = (v > 0.f) ? v : (__expf(v) - 1.f); vsh[r0 + 0][f] = v;
    hmid_b[(long)(n + 0) * 64 + f] = (ushortT)f2b(v);
    v = accB; v = (v > 0.f) ? v : (__expf(v) - 1.f); vsh[r0 + 1][f] = v;
    hmid_b[(long)(n + 1) * 64 + f] = (ushortT)f2b(v);
    v = accC; v = (v > 0.f) ? v : (__expf(v) - 1.f); vsh[r0 + 2][f] = v;
    hmid_b[(long)(n + 2) * 64 + f] = (ushortT)f2b(v);
    v = accD; v = (v > 0.f) ? v : (__expf(v) - 1.f); vsh[r0 + 3][f] = v;
    hmid_b[(long)(n + 3) * 64 + f] = (ushortT)f2b(v);
    __syncthreads();
    if (t < 128) {
        int nl = t >> 3;               // local node 0..15
        int j = t & 7;                 // 0..3 -> u2s head j ; 4..7 -> u2d head j-4
        const float* uv = (j < 4) ? (u2s + (j & 3) * 64) : (u2d + (j & 3) * 64);
        float acc = 0.f;
#pragma unroll 8
        for (int f2 = 0; f2 < 64; f2++) acc = fmaf(vsh[nl][f2], uv[f2], acc);
        int nn = n0 + nl;
        if (j < 4) asb[nn * 4 + j] = acc;
        else       adb[nn * 4 + (j & 3)] = acc;
    }
}

// ---------------- layer-2 GEMM + fused start head + pooled partials ----------------
__global__ __launch_bounds__(256) void gemm2s_kernel(
    const float* __restrict__ agg2, const float* __restrict__ W2,
    const float* __restrict__ b2, const float* __restrict__ cs,
    const float* __restrict__ sW1, const float* __restrict__ sW2,
    const float* __restrict__ sb2, float* __restrict__ out,
    float* __restrict__ pooledP) {
    __shared__ float sagg[16 * 256];   // 16 KB
    __shared__ float hrow[4][4][64];
    __shared__ float ps[4][64];
    int t = threadIdx.x;
    int cb = blockIdx.x * 16;          // NCAND = 16 * 512
    {
        const float4* src = (const float4*)(agg2 + (long)cb * 256);
        float4* dst = (float4*)sagg;
        dst[t] = src[t];
        dst[t + 256] = src[t + 256];
        dst[t + 512] = src[t + 512];
        dst[t + 768] = src[t + 768];
    }
    __syncthreads();
    int wslot = t >> 6;
    int f = t & 63;
    int r0 = wslot * 4;
    int c0 = cb + r0;
    float bb = b2[f];
    float accA = bb, accB = bb, accC = bb, accD = bb;
    const float* pA = sagg + (r0 + 0) * 256;
    const float* pB = sagg + (r0 + 1) * 256;
    const float* pC = sagg + (r0 + 2) * 256;
    const float* pD = sagg + (r0 + 3) * 256;
    for (int k = 0; k < 64; k++) {
        const float* wr = W2 + k * 256 + f;
        float w0 = wr[0], w1 = wr[64], w2 = wr[128], w3 = wr[192];
        float4 aA = *(const float4*)(pA + k * 4);
        float4 aB = *(const float4*)(pB + k * 4);
        float4 aC = *(const float4*)(pC + k * 4);
        float4 aD = *(const float4*)(pD + k * 4);
        accA = fmaf(aA.x, w0, accA); accA = fmaf(aA.y, w1, accA);
        accA = fmaf(aA.z, w2, accA); accA = fmaf(aA.w, w3, accA);
        accB = fmaf(aB.x, w0, accB); accB = fmaf(aB.y, w1, accB);
        accB = fmaf(aB.z, w2, accB); accB = fmaf(aB.w, w3, accB);
        accC = fmaf(aC.x, w0, accC); accC = fmaf(aC.y, w1, accC);
        accC = fmaf(aC.z, w2, accC); accC = fmaf(aC.w, w3, accC);
        accD = fmaf(aD.x, w0, accD); accD = fmaf(aD.y, w1, accD);
        accD = fmaf(aD.z, w2, accD); accD = fmaf(aD.w, w3, accD);
    }
    float v, vA, vB, vC, vD;
    v = accA; vA = (v > 0.f) ? v : (__expf(v) - 1.f);
    v = accB; vB = (v > 0.f) ? v : (__expf(v) - 1.f);
    v = accC; vC = (v > 0.f) ? v : (__expf(v) - 1.f);
    v = accD; vD = (v > 0.f) ? v : (__expf(v) - 1.f);
    hrow[wslot][0][f] = vA;
    hrow[wslot][1][f] = vB;
    hrow[wslot][2][f] = vC;
    hrow[wslot][3][f] = vD;
    ps[wslot][f] = vA + vB + vC + vD;
    asm volatile("" ::: "memory");   // wave-private LDS region: in-order per wave
    float sw2 = sW2[f];
    float csf = cs[f];
#pragma unroll
    for (int c = 0; c < 4; c++) {
        float hid = csf;
#pragma unroll 8
        for (int k = 0; k < 64; k++) hid = fmaf(hrow[wslot][c][k], sW1[k * 64 + f], hid);
        hid = fmaxf(hid, 0.f) * sw2;
#pragma unroll
        for (int o = 32; o > 0; o >>= 1) hid += __shfl_xor(hid, o, 64);
        if (f == 0) out[c0 + c] = hid + sb2[0];
    }
    __syncthreads();
    if (t < 64)
        atomicAdd(&pooledP[(blockIdx.x & 7) * 64 + t],
                  ps[0][t] + ps[1][t] + ps[2][t] + ps[3][t]);
}

// ---------------- tail ----------------

__global__ void length_kernel(const float* __restrict__ pooledP, const float* __restrict__ lW1,
                              const float* __restrict__ cl, const float* __restrict__ lW2,
                              const float* __restrict__ lb2, float* __restrict__ out) {
    __shared__ float hid[64];
    __shared__ float pl[64];
    int t = threadIdx.x;  // 64
    float pk = 0.f;
#pragma unroll
    for (int s = 0; s < 8; s++) pk += pooledP[s * 64 + t];
    pl[t] = pk * (1.f / NCAND);
    __syncthreads();
    float a = cl[t];
    for (int k = 0; k < 64; k++) a += pl[k] * lW1[k * 64 + t];
    hid[t] = fmaxf(a, 0.f);
    __syncthreads();
    if (t < NBUCK) {
        float acc = lb2[t];
        for (int j = 0; j < 64; j++) acc += hid[j] * lW2[j * NBUCK + t];
        out[NCAND + t] = acc;
    }
}

extern "C" void kernel_launch(void* const* d_in, const int* in_sizes, int n_in,
                              void* d_out, int out_size, void* d_ws, size_t ws_size,
                              hipStream_t stream) {
    const float* x     = (const float*)d_in[0];
    const int*   ei    = (const int*)d_in[1];
    const float* donor = (const float*)d_in[2];
    const int*   cand  = (const int*)d_in[3];
    const float* W1    = (const float*)d_in[4];
    const float* as1   = (const float*)d_in[5];
    const float* ad1   = (const float*)d_in[6];
    const float* b1    = (const float*)d_in[7];
    const float* W2    = (const float*)d_in[8];
    const float* as2   = (const float*)d_in[9];
    const float* ad2   = (const float*)d_in[10];
    const float* b2    = (const float*)d_in[11];
    const float* sW1   = (const float*)d_in[12];
    const float* sb1   = (const float*)d_in[13];
    const float* sW2   = (const float*)d_in[14];
    const float* sb2   = (const float*)d_in[15];
    const float* lW1   = (const float*)d_in[16];
    const float* lb1   = (const float*)d_in[17];
    const float* lW2   = (const float*)d_in[18];
    const float* lb2   = (const float*)d_in[19];
    float* out = (float*)d_out;

    float* wsf     = (float*)d_ws;
    float* agg1    = wsf;                      // 50000*128 = 6,400,000
    float* agg2    = agg1 + 6400000;           // 8192*256 = 2,097,152
    float* asb     = agg2 + 2097152;           // 200,000
    float* adb     = asb + 200000;             // 200,000
    float* u2s     = adb + 200000;             // 256
    float* u2d     = u2s + 256;                // 256
    float* cs      = u2d + 256;                // 64
    float* cl      = cs + 64;                  // 64
    float* pooledP = cl + 64;                  // 512 (8 slices x 64)
    unsigned* xbu   = (unsigned*)(pooledP + 512);   // 50000*16 uints (bf16 x, padded to 32)
    ushortT* hmid_b = (ushortT*)(xbu + 800000);     // 50000*64 ushorts
    int* degS = (int*)(hmid_b + 3200000);      // 50000 (slice-blocked: (d&7)*6250 + (d>>3))
    ushortT* csr16 = (ushortT*)(degS + 50000); // 50000*64 u16, rows at degslot(d)*64
    // total ~52 MB

    const int* e_src = ei;
    const int* e_dst = ei + N_EDGES;

    hipMemsetAsync(degS, 0, N_NODES * sizeof(int), stream);
    kernelA<<<FILLB + 196 + 1, 256, 0, stream>>>(
        e_src, e_dst, degS, csr16, x, W1, as1, ad1, W2, as2, ad2,
        donor, sW1, sb1, lW1, lb1, xbu, asb, adb, u2s, u2d, cs, cl, pooledP);

    msg_kernel<32, false><<<(N_NODES + 3) / 4, 256, 0, stream>>>(
        (const ushortT*)xbu, asb, adb, degS, csr16, cand, agg1, N_NODES);
    gemm1_kernel<<<(N_NODES / 16), 256, 0, stream>>>(agg1, W1, b1, u2s, u2d,
                                                     hmid_b, asb, adb);       // 3125 blocks
    msg_kernel<64, true><<<(NCAND + 3) / 4, 256, 0, stream>>>(
        hmid_b, asb, adb, degS, csr16, cand, agg2, NCAND);
    gemm2s_kernel<<<(NCAND / 16), 256, 0, stream>>>(agg2, W2, b2, cs, sW1, sW2, sb2,
                                                    out, pooledP);              // 512 blocks
    length_kernel<<<1, 64, 0, stream>>>(pooledP, lW1, cl, lW2, lb2, out);
}

// Round 20
// 142.165 us; speedup vs baseline: 1.0195x; 1.0195x over previous
//
#include <hip/hip_runtime.h>

#define N_NODES 50000
#define N_EDGES 800000
#define N_TOT   850000   // edges + self loops
#define FIN 27
#define NCAND 8192
#define CTXD 32
#define NBUCK 7
#define NEG 0.2f
#define MAXDEG 64        // padded CSR row; P(deg>64) ~ 1e-19 per node at lambda=17
#define NSLICE 8         // dst slices = XCD count; slice = dst & 7
#define SL_N 6250        // nodes per slice (50000/8)
#define EPB 1024         // edges scanned per fill block
#define NCHUNK 831       // ceil(850000/1024)
#define FILLB (NCHUNK * NSLICE)   // 6648 fill blocks

typedef unsigned short ushortT;

__device__ __forceinline__ float bfu(ushortT u) { return __uint_as_float(((unsigned)u) << 16); }
__device__ __forceinline__ unsigned f2b(float f) {
    unsigned bits = __float_as_uint(f);
    return (bits + 0x7FFFu + ((bits >> 16) & 1u)) >> 16;
}
// slot for node d: slice-exclusive contiguous block (degS and csr16 rows)
__device__ __forceinline__ int degslot(int d) { return (d & 7) * SL_N + (d >> 3); }

// ============ Kernel A: XCD-sliced scatter CSR fill || prep1 || misc precompute ============
// Scatter-fill floor MEASURED at ~50us across 7 variants (plain/sliced/contiguous/
// nt-load/nt-store/LDS-binned x2, R8-R19): 850K random atomic+2B-store pairs are
// line-fill-latency-bound on gfx950; locality layouts and cache-policy hints are all
// neutral-or-worse. Plain store is the best-traffic variant — keep it.
__global__ __launch_bounds__(256) void kernelA(
    const int* __restrict__ e_src, const int* __restrict__ e_dst,
    int* __restrict__ degS, ushortT* __restrict__ csr16,
    const float* __restrict__ x, const float* __restrict__ W1,
    const float* __restrict__ as1, const float* __restrict__ ad1,
    const float* __restrict__ W2, const float* __restrict__ as2, const float* __restrict__ ad2,
    const float* __restrict__ donor, const float* __restrict__ sW1, const float* __restrict__ sb1,
    const float* __restrict__ lW1, const float* __restrict__ lb1,
    unsigned* __restrict__ xbu, float* __restrict__ asb, float* __restrict__ adb,
    float* __restrict__ u2s, float* __restrict__ u2d,
    float* __restrict__ cs, float* __restrict__ cl, float* __restrict__ pooledP) {
    __shared__ float u1[256];
    int bid = blockIdx.x;
    int t = threadIdx.x;

    if (bid < FILLB) {
        // ---- sliced scatter fill (slice pinned to XCD by round-robin dispatch) ----
        int chunk = bid >> 3;
        int slice = bid & 7;
        int e0 = chunk * EPB;
#pragma unroll
        for (int i = 0; i < EPB / 256; i++) {
            int e = e0 + i * 256 + t;
            if (e < N_TOT) {
                int d = (e < N_EDGES) ? e_dst[e] : (e - N_EDGES);
                if ((d & 7) == slice) {
                    int s = (e < N_EDGES) ? e_src[e] : d;
                    int slot = degslot(d);
                    int p = atomicAdd(&degS[slot], 1);
                    if (p < MAXDEG) csr16[((long)slot << 6) + p] = (ushortT)s;
                }
            }
        }
    } else if (bid < FILLB + 196) {
        // ---- prep1: compute u1 locally, then per-node dots + bf16 pack ----
        if (t < 4 * FIN) {
            int h = t / FIN, k = t % FIN;
            float s = 0.f;
            for (int f = 0; f < 64; f++) s += W1[k * 256 + h * 64 + f] * as1[h * 64 + f];
            u1[h * 32 + k] = s;
        } else if (t >= 128 && t < 128 + 4 * FIN) {
            int tt = t - 128;
            int h = tt / FIN, k = tt % FIN;
            float d = 0.f;
            for (int f = 0; f < 64; f++) d += W1[k * 256 + h * 64 + f] * ad1[h * 64 + f];
            u1[128 + h * 32 + k] = d;
        }
        __syncthreads();
        int n = (bid - FILLB) * 256 + t;
        if (n < N_NODES) {
            float xr[FIN];
#pragma unroll
            for (int k = 0; k < FIN; k++) xr[k] = x[(long)n * FIN + k];
            float s0 = 0, s1 = 0, s2 = 0, s3 = 0, d0 = 0, d1 = 0, d2 = 0, d3 = 0;
#pragma unroll
            for (int k = 0; k < FIN; k++) {
                float xv = xr[k];
                s0 = fmaf(xv, u1[0 * 32 + k], s0);
                s1 = fmaf(xv, u1[1 * 32 + k], s1);
                s2 = fmaf(xv, u1[2 * 32 + k], s2);
                s3 = fmaf(xv, u1[3 * 32 + k], s3);
                d0 = fmaf(xv, u1[128 + 0 * 32 + k], d0);
                d1 = fmaf(xv, u1[128 + 1 * 32 + k], d1);
                d2 = fmaf(xv, u1[128 + 2 * 32 + k], d2);
                d3 = fmaf(xv, u1[128 + 3 * 32 + k], d3);
            }
            float4 sv; sv.x = s0; sv.y = s1; sv.z = s2; sv.w = s3;
            float4 dv; dv.x = d0; dv.y = d1; dv.z = d2; dv.w = d3;
            *(float4*)(asb + n * 4) = sv;
            *(float4*)(adb + n * 4) = dv;
#pragma unroll
            for (int i = 0; i < 16; i++) {
                float a = (2 * i < FIN) ? xr[2 * i] : 0.f;
                float b = (2 * i + 1 < FIN) ? xr[2 * i + 1] : 0.f;
                xbu[(long)n * 16 + i] = f2b(a) | (f2b(b) << 16);
            }
        }
    } else {
        // ---- misc precompute ----
        pooledP[t] = 0.f;
        pooledP[256 + t] = 0.f;
        {
            int h = t >> 6, k = t & 63;
            float s = 0.f, d = 0.f;
            for (int f = 0; f < 64; f++) {
                float w = W2[k * 256 + h * 64 + f];
                s += w * as2[h * 64 + f];
                d += w * ad2[h * 64 + f];
            }
            u2s[h * 64 + k] = s;
            u2d[h * 64 + k] = d;
        }
        if (t < 64) {
            float a = sb1[t];
            float b = lb1[t];
            for (int m = 0; m < CTXD; m++) {
                float d = donor[m];
                a += d * sW1[(64 + m) * 64 + t];
                b += d * lW1[(64 + m) * 64 + t];
            }
            cs[t] = a;
            cl[t] = b;
        }
    }
}

// ---------------- fused attention + aggregation (wave per dst, single padded tile) ----------------
template <int FEATS, bool USECAND>
__global__ __launch_bounds__(256) void msg_kernel(
    const ushortT* __restrict__ feat, const float* __restrict__ asb,
    const float* __restrict__ adb, const int* __restrict__ degS,
    const ushortT* __restrict__ csr16, const int* __restrict__ cand,
    float* __restrict__ agg, int ndst) {
    __shared__ float wls[4][256];
    __shared__ int   sls[4][64];
    int wslot = threadIdx.x >> 6;
    int lane = threadIdx.x & 63;
    int wid = (blockIdx.x * 256 + threadIdx.x) >> 6;
    if (wid >= ndst) return;
    int dst = USECAND ? cand[wid] : wid;
    const float4 ad4 = *(const float4*)(adb + dst * 4);
    int slot = degslot(dst);
    int cnt = min(degS[slot], MAXDEG);
    float a0 = 0, a1 = 0, a2 = 0, a3 = 0;
    float d0 = 0, d1 = 0, d2 = 0, d3 = 0;
    const int f = lane & (FEATS - 1);
    {
        float w0 = 0, w1 = 0, w2 = 0, w3 = 0;
        int sj = dst;
        if (lane < cnt) {
            sj = (int)csr16[((long)slot << 6) + lane];
            const float4 as4 = *(const float4*)(asb + sj * 4);
            float e0 = as4.x + ad4.x; e0 = fmaxf(e0, NEG * e0); w0 = __expf(e0);
            float e1 = as4.y + ad4.y; e1 = fmaxf(e1, NEG * e1); w1 = __expf(e1);
            float e2 = as4.z + ad4.z; e2 = fmaxf(e2, NEG * e2); w2 = __expf(e2);
            float e3 = as4.w + ad4.w; e3 = fmaxf(e3, NEG * e3); w3 = __expf(e3);
            d0 = w0; d1 = w1; d2 = w2; d3 = w3;
        }
        float4 wv; wv.x = w0; wv.y = w1; wv.z = w2; wv.w = w3;
        *(float4*)&wls[wslot][lane * 4] = wv;
        sls[wslot][lane] = sj;
        asm volatile("" ::: "memory");   // keep DS write before DS reads (in-order per wave)
        if (FEATS == 32) {
            int iters = (cnt + 1) >> 1;
            int half = lane >> 5;
#pragma unroll 4
            for (int it = 0; it < iters; ++it) {
                int e = it * 2 + half;              // pad slot has w=0, src=dst
                int s = sls[wslot][e];
                float4 w4 = *(const float4*)&wls[wslot][e * 4];
                float fv = bfu(feat[(long)s * FEATS + f]);
                a0 = fmaf(w4.x, fv, a0);
                a1 = fmaf(w4.y, fv, a1);
                a2 = fmaf(w4.z, fv, a2);
                a3 = fmaf(w4.w, fv, a3);
            }
        } else {
#pragma unroll 4
            for (int e = 0; e < cnt; ++e) {
                int s = sls[wslot][e];
                float4 w4 = *(const float4*)&wls[wslot][e * 4];
                float fv = bfu(feat[(long)s * FEATS + f]);
                a0 = fmaf(w4.x, fv, a0);
                a1 = fmaf(w4.y, fv, a1);
                a2 = fmaf(w4.z, fv, a2);
                a3 = fmaf(w4.w, fv, a3);
            }
        }
    }
#pragma unroll
    for (int o = 32; o > 0; o >>= 1) {
        d0 += __shfl_xor(d0, o, 64);
        d1 += __shfl_xor(d1, o, 64);
        d2 += __shfl_xor(d2, o, 64);
        d3 += __shfl_xor(d3, o, 64);
    }
    if (FEATS == 32) {
        a0 += __shfl_xor(a0, 32, 64);
        a1 += __shfl_xor(a1, 32, 64);
        a2 += __shfl_xor(a2, 32, 64);
        a3 += __shfl_xor(a3, 32, 64);
    }
    if (lane < FEATS) {
        float4 r;
        r.x = a0 * (0.25f / d0);
        r.y = a1 * (0.25f / d1);
        r.z = a2 * (0.25f / d2);
        r.w = a3 * (0.25f / d3);
        *(float4*)(agg + (long)wid * (FEATS * 4) + lane * 4) = r;
    }
}

// ---------------- post-aggregation GEMM, layer 1 + fused layer-2 attention dots ----------------
__global__ __launch_bounds__(256) void gemm1_kernel(
    const float* __restrict__ agg1, const float* __restrict__ W1,
    const float* __restrict__ b1, const float* __restrict__ u2s,
    const float* __restrict__ u2d, ushortT* __restrict__ hmid_b,
    float* __restrict__ asb, float* __restrict__ adb) {
    __shared__ float sagg[16 * 128];   // 8 KB
    __shared__ float vsh[16][65];      // padded (conflict-free column reads)
    int t = threadIdx.x;
    int n0 = blockIdx.x * 16;          // N_NODES = 16 * 3125
    {
        const float4* src = (const float4*)(agg1 + (long)n0 * 128);
        float4* dst = (float4*)sagg;
        dst[t] = src[t];
        dst[t + 256] = src[t + 256];
    }
    __syncthreads();
    int r0 = (t >> 6) * 4;             // wave's first node (local)
    int f = t & 63;
    float bb = b1[f];
    float accA = bb, accB = bb, accC = bb, accD = bb;
    const float* pA = sagg + (r0 + 0) * 128;
    const float* pB = sagg + (r0 + 1) * 128;
    const float* pC = sagg + (r0 + 2) * 128;
    const float* pD = sagg + (r0 + 3) * 128;
#pragma unroll
    for (int k = 0; k < FIN; k++) {
        const float* wr = W1 + k * 256 + f;
        float w0 = wr[0], w1 = wr[64], w2 = wr[128], w3 = wr[192];
        float4 aA = *(const float4*)(pA + k * 4);
        float4 aB = *(const float4*)(pB + k * 4);
        float4 aC = *(const float4*)(pC + k * 4);
        float4 aD = *(const float4*)(pD + k * 4);
        accA = fmaf(aA.x, w0, accA); accA = fmaf(aA.y, w1, accA);
        accA = fmaf(aA.z, w2, accA); accA = fmaf(aA.w, w3, accA);
        accB = fmaf(aB.x, w0, accB); accB = fmaf(aB.y, w1, accB);
        accB = fmaf(aB.z, w2, accB); accB = fmaf(aB.w, w3, accB);
        accC = fmaf(aC.x, w0, accC); accC = fmaf(aC.y, w1, accC);
        accC = fmaf(aC.z, w2, accC); accC = fmaf(aC.w, w3, accC);
        accD = fmaf(aD.x, w0, accD); accD = fmaf(aD.y, w1, accD);
        accD = fmaf(aD.z, w2, accD); accD = fmaf(aD.w, w3, accD);
    }
    int n = n0 + r0;
    float v;
    v = accA; v = (v > 0.f) ? v : (__expf(v) - 1.f); vsh[r0 + 0][f] = v;
    hmid_b[(long)(n + 0) * 64 + f] = (ushortT)f2b(v);
    v = accB; v = (v > 0.f) ? v : (__expf(v) - 1.f); vsh[r0 + 1][f] = v;
    hmid_b[(long)(n + 1) * 64 + f] = (ushortT)f2b(v);
    v = accC; v = (v > 0.f) ? v : (__expf(v) - 1.f); vsh[r0 + 2][f] = v;
    hmid_b[(long)(n + 2) * 64 + f] = (ushortT)f2b(v);
    v = accD; v = (v > 0.f) ? v : (__expf(v) - 1.f); vsh[r0 + 3][f] = v;
    hmid_b[(long)(n + 3) * 64 + f] = (ushortT)f2b(v);
    __syncthreads();
    if (t < 128) {
        int nl = t >> 3;               // local node 0..15
        int j = t & 7;                 // 0..3 -> u2s head j ; 4..7 -> u2d head j-4
        const float* uv = (j < 4) ? (u2s + (j & 3) * 64) : (u2d + (j & 3) * 64);
        float acc = 0.f;
#pragma unroll 8
        for (int f2 = 0; f2 < 64; f2++) acc = fmaf(vsh[nl][f2], uv[f2], acc);
        int nn = n0 + nl;
        if (j < 4) asb[nn * 4 + j] = acc;
        else       adb[nn * 4 + (j & 3)] = acc;
    }
}

// ---------------- layer-2 GEMM + fused start head + pooled partials ----------------
__global__ __launch_bounds__(256) void gemm2s_kernel(
    const float* __restrict__ agg2, const float* __restrict__ W2,
    const float* __restrict__ b2, const float* __restrict__ cs,
    const float* __restrict__ sW1, const float* __restrict__ sW2,
    const float* __restrict__ sb2, float* __restrict__ out,
    float* __restrict__ pooledP) {
    __shared__ float sagg[16 * 256];   // 16 KB
    __shared__ float hrow[4][4][64];
    __shared__ float ps[4][64];
    int t = threadIdx.x;
    int cb = blockIdx.x * 16;          // NCAND = 16 * 512
    {
        const float4* src = (const float4*)(agg2 + (long)cb * 256);
        float4* dst = (float4*)sagg;
        dst[t] = src[t];
        dst[t + 256] = src[t + 256];
        dst[t + 512] = src[t + 512];
        dst[t + 768] = src[t + 768];
    }
    __syncthreads();
    int wslot = t >> 6;
    int f = t & 63;
    int r0 = wslot * 4;
    int c0 = cb + r0;
    float bb = b2[f];
    float accA = bb, accB = bb, accC = bb, accD = bb;
    const float* pA = sagg + (r0 + 0) * 256;
    const float* pB = sagg + (r0 + 1) * 256;
    const float* pC = sagg + (r0 + 2) * 256;
    const float* pD = sagg + (r0 + 3) * 256;
    for (int k = 0; k < 64; k++) {
        const float* wr = W2 + k * 256 + f;
        float w0 = wr[0], w1 = wr[64], w2 = wr[128], w3 = wr[192];
        float4 aA = *(const float4*)(pA + k * 4);
        float4 aB = *(const float4*)(pB + k * 4);
        float4 aC = *(const float4*)(pC + k * 4);
        float4 aD = *(const float4*)(pD + k * 4);
        accA = fmaf(aA.x, w0, accA); accA = fmaf(aA.y, w1, accA);
        accA = fmaf(aA.z, w2, accA); accA = fmaf(aA.w, w3, accA);
        accB = fmaf(aB.x, w0, accB); accB = fmaf(aB.y, w1, accB);
        accB = fmaf(aB.z, w2, accB); accB = fmaf(aB.w, w3, accB);
        accC = fmaf(aC.x, w0, accC); accC = fmaf(aC.y, w1, accC);
        accC = fmaf(aC.z, w2, accC); accC = fmaf(aC.w, w3, accC);
        accD = fmaf(aD.x, w0, accD); accD = fmaf(aD.y, w1, accD);
        accD = fmaf(aD.z, w2, accD); accD = fmaf(aD.w, w3, accD);
    }
    float v, vA, vB, vC, vD;
    v = accA; vA = (v > 0.f) ? v : (__expf(v) - 1.f);
    v = accB; vB = (v > 0.f) ? v : (__expf(v) - 1.f);
    v = accC; vC = (v > 0.f) ? v : (__expf(v) - 1.f);
    v = accD; vD = (v > 0.f) ? v : (__expf(v) - 1.f);
    hrow[wslot][0][f] = vA;
    hrow[wslot][1][f] = vB;
    hrow[wslot][2][f] = vC;
    hrow[wslot][3][f] = vD;
    ps[wslot][f] = vA + vB + vC + vD;
    asm volatile("" ::: "memory");   // wave-private LDS region: in-order per wave
    float sw2 = sW2[f];
    float csf = cs[f];
#pragma unroll
    for (int c = 0; c < 4; c++) {
        float hid = csf;
#pragma unroll 8
        for (int k = 0; k < 64; k++) hid = fmaf(hrow[wslot][c][k], sW1[k * 64 + f], hid);
        hid = fmaxf(hid, 0.f) * sw2;
#pragma unroll
        for (int o = 32; o > 0; o >>= 1) hid += __shfl_xor(hid, o, 64);
        if (f == 0) out[c0 + c] = hid + sb2[0];
    }
    __syncthreads();
    if (t < 64)
        atomicAdd(&pooledP[(blockIdx.x & 7) * 64 + t],
                  ps[0][t] + ps[1][t] + ps[2][t] + ps[3][t]);
}

// ---------------- tail ----------------

__global__ void length_kernel(const float* __restrict__ pooledP, const float* __restrict__ lW1,
                              const float* __restrict__ cl, const float* __restrict__ lW2,
                              const float* __restrict__ lb2, float* __restrict__ out) {
    __shared__ float hid[64];
    __shared__ float pl[64];
    int t = threadIdx.x;  // 64
    float pk = 0.f;
#pragma unroll
    for (int s = 0; s < 8; s++) pk += pooledP[s * 64 + t];
    pl[t] = pk * (1.f / NCAND);
    __syncthreads();
    float a = cl[t];
    for (int k = 0; k < 64; k++) a += pl[k] * lW1[k * 64 + t];
    hid[t] = fmaxf(a, 0.f);
    __syncthreads();
    if (t < NBUCK) {
        float acc = lb2[t];
        for (int j = 0; j < 64; j++) acc += hid[j] * lW2[j * NBUCK + t];
        out[NCAND + t] = acc;
    }
}

extern "C" void kernel_launch(void* const* d_in, const int* in_sizes, int n_in,
                              void* d_out, int out_size, void* d_ws, size_t ws_size,
                              hipStream_t stream) {
    const float* x     = (const float*)d_in[0];
    const int*   ei    = (const int*)d_in[1];
    const float* donor = (const float*)d_in[2];
    const int*   cand  = (const int*)d_in[3];
    const float* W1    = (const float*)d_in[4];
    const float* as1   = (const float*)d_in[5];
    const float* ad1   = (const float*)d_in[6];
    const float* b1    = (const float*)d_in[7];
    const float* W2    = (const float*)d_in[8];
    const float* as2   = (const float*)d_in[9];
    const float* ad2   = (const float*)d_in[10];
    const float* b2    = (const float*)d_in[11];
    const float* sW1   = (const float*)d_in[12];
    const float* sb1   = (const float*)d_in[13];
    const float* sW2   = (const float*)d_in[14];
    const float* sb2   = (const float*)d_in[15];
    const float* lW1   = (const float*)d_in[16];
    const float* lb1   = (const float*)d_in[17];
    const float* lW2   = (const float*)d_in[18];
    const float* lb2   = (const float*)d_in[19];
    float* out = (float*)d_out;

    float* wsf     = (float*)d_ws;
    float* agg1    = wsf;                      // 50000*128 = 6,400,000
    float* agg2    = agg1 + 6400000;           // 8192*256 = 2,097,152
    float* asb     = agg2 + 2097152;           // 200,000
    float* adb     = asb + 200000;             // 200,000
    float* u2s     = adb + 200000;             // 256
    float* u2d     = u2s + 256;                // 256
    float* cs      = u2d + 256;                // 64
    float* cl      = cs + 64;                  // 64
    float* pooledP = cl + 64;                  // 512 (8 slices x 64)
    unsigned* xbu   = (unsigned*)(pooledP + 512);   // 50000*16 uints (bf16 x, padded to 32)
    ushortT* hmid_b = (ushortT*)(xbu + 800000);     // 50000*64 ushorts
    int* degS = (int*)(hmid_b + 3200000);      // 50000 (slice-blocked: (d&7)*6250 + (d>>3))
    ushortT* csr16 = (ushortT*)(degS + 50000); // 50000*64 u16, rows at degslot(d)*64
    // total ~52 MB

    const int* e_src = ei;
    const int* e_dst = ei + N_EDGES;

    hipMemsetAsync(degS, 0, N_NODES * sizeof(int), stream);
    kernelA<<<FILLB + 196 + 1, 256, 0, stream>>>(
        e_src, e_dst, degS, csr16, x, W1, as1, ad1, W2, as2, ad2,
        donor, sW1, sb1, lW1, lb1, xbu, asb, adb, u2s, u2d, cs, cl, pooledP);

    msg_kernel<32, false><<<(N_NODES + 3) / 4, 256, 0, stream>>>(
        (const ushortT*)xbu, asb, adb, degS, csr16, cand, agg1, N_NODES);
    gemm1_kernel<<<(N_NODES / 16), 256, 0, stream>>>(agg1, W1, b1, u2s, u2d,
                                                     hmid_b, asb, adb);       // 3125 blocks
    msg_kernel<64, true><<<(NCAND + 3) / 4, 256, 0, stream>>>(
        hmid_b, asb, adb, degS, csr16, cand, agg2, NCAND);
    gemm2s_kernel<<<(NCAND / 16), 256, 0, stream>>>(agg2, W2, b2, cs, sW1, sW2, sb2,
                                                    out, pooledP);              // 512 blocks
    length_kernel<<<1, 64, 0, stream>>>(pooledP, lW1, cl, lW2, lb2, out);
}